// Round 2
// baseline (164.227 us; speedup 1.0000x reference)
//
#include <hip/hip_runtime.h>
#include <hip/hip_bf16.h>
#include <cstdint>
#include <cstddef>

#define BATCH 4096
#define INC   1024
#define OUTC  1024
#define NB    8
#define KDIM  (INC * NB)   // 8192 (elements == bytes in i8)

// GEMM tile: 256x256 block, BK=64 bytes i8, 8 waves (2M x 4N), wave tile 128x64
// (8x4 frags of 16x16x64 i8). Double-buffered STATIC LDS (2 x 32 KiB slots = 64 KiB,
// no dynamic-LDS attribute API), burst prefetch of step t+1 at top of step t,
// 2 phased MFMA clusters per step with raw s_barrier + setprio (T3+T5),
// XOR-swizzled 16B k-groups (T2), bijective XCD swizzle (T1).
#define BM 256
#define BN 256
#define BKB 64                  // k-bytes per step
#define SPLITS 4
#define KZ (KDIM / SPLITS)      // 2048 bytes per z
#define KSTEPS (KZ / BKB)       // 32 even steps, no tail
#define GRID_BLOCKS ((OUTC / BN) * (BATCH / BM) * SPLITS)   // 4*16*4 = 256 = 1 block/CU

// prep dispatch partition: expand | fused rowmax+quant (one block per coeff row)
#define EXPAND_BLOCKS  ((BATCH * INC) / 256)   // 16384
#define QUANT_BLOCKS   OUTC                    // 1024
#define PREP_BLOCKS    (EXPAND_BLOCKS + QUANT_BLOCKS)

typedef int   v4i __attribute__((ext_vector_type(4)));
typedef char  v8c __attribute__((ext_vector_type(8)));
typedef short v8s __attribute__((ext_vector_type(8)));

__device__ __forceinline__ unsigned short f2bf(float f) {
  union { float f; unsigned u; } v; v.f = f;
  unsigned r = v.u + 0x7fffu + ((v.u >> 16) & 1u);  // round-to-nearest-even
  return (unsigned short)(r >> 16);
}
__device__ __forceinline__ float bf2f(unsigned short h) {
  union { unsigned u; float f; } v; v.u = ((unsigned)h) << 16; return v.f;
}

// async 16B global -> LDS (DMA; LDS dest = wave-uniform base + lane*16)
__device__ __forceinline__ void gld16(const char* g, char* l) {
  __builtin_amdgcn_global_load_lds(
      (const __attribute__((address_space(1))) unsigned int*)g,
      (__attribute__((address_space(3))) unsigned int*)l, 16, 0, 0);
}

// ---------------- Phase 1 (fused dispatch): expand basis | rowmax+quantize coeffs -------
// expand: basis_m = sigmoid(2*s*(u-c_m)); equispaced centers + uniform slope ->
//   e_m = e0*R^m (2 exp2 total). Affine quant qa = rint(basis*254-127).
// quant: one block per coeff row; row (32KB) held in registers across max-reduce,
//   then quantized: qc = rint(c*127/M). qcsum computed in-block (no atomics/memset).
__global__ __launch_bounds__(256) void prep_kernel(
    const float* __restrict__ x, const float4* __restrict__ coeffs4,
    const float* __restrict__ centers, const float* __restrict__ slopes,
    const float* __restrict__ alpha, const float* __restrict__ beta,
    char* __restrict__ Ai8, int* __restrict__ Ci8i,
    float* __restrict__ maxrow, int* __restrict__ qcsum) {
  const int blk = blockIdx.x;
  const int tid = threadIdx.x;
  if (blk < EXPAND_BLOCKS) {
    const int idx = blk * 256 + tid;          // (b,i) pair
    const int i = idx & (INC - 1);
    const float u = alpha[i] * x[idx] + beta[i];
    const float s0 = slopes[i * NB];
    const float c0 = centers[i * NB];
    const float c1 = centers[i * NB + 1];
    const float L2E2 = 2.8853900817779268f;   // 2*log2(e)
    const float a2 = L2E2 * s0;
    float e = __builtin_amdgcn_exp2f(a2 * (c0 - u));   // inf -> rcp -> 0: correct limit
    const float R = __builtin_amdgcn_exp2f(a2 * (c1 - c0));
    v8c q;
#pragma unroll
    for (int m = 0; m < 8; ++m) {
      float basis = __builtin_amdgcn_rcpf(1.0f + e);
      q[m] = (char)(int)rintf(basis * 254.0f - 127.0f);
      e *= R;
    }
    *(v8c*)(Ai8 + (size_t)idx * 8) = q;   // 8B coalesced store
  } else {
    const int o = blk - EXPAND_BLOCKS;
    const float4* row = coeffs4 + (size_t)o * (KDIM / 4);
    float4 v[8];
    float m = 0.0f;
#pragma unroll
    for (int j = 0; j < 8; ++j) {
      v[j] = row[tid + 256 * j];
      m = fmaxf(m, fmaxf(fmaxf(fabsf(v[j].x), fabsf(v[j].y)),
                         fmaxf(fabsf(v[j].z), fabsf(v[j].w))));
    }
#pragma unroll
    for (int off = 32; off; off >>= 1) m = fmaxf(m, __shfl_xor(m, off));
    __shared__ float wm[4];
    __shared__ int   wq[4];
    if ((tid & 63) == 0) wm[tid >> 6] = m;
    __syncthreads();
    const float M = fmaxf(fmaxf(fmaxf(wm[0], wm[1]), fmaxf(wm[2], wm[3])), 1e-30f);
    const float s = 127.0f / M;
    int qs = 0;
#pragma unroll
    for (int j = 0; j < 8; ++j) {
      int q0 = (int)rintf(v[j].x * s), q1 = (int)rintf(v[j].y * s);
      int q2 = (int)rintf(v[j].z * s), q3 = (int)rintf(v[j].w * s);
      Ci8i[(size_t)o * (KDIM / 4) + tid + 256 * j] =
          (q0 & 0xFF) | ((q1 & 0xFF) << 8) | ((q2 & 0xFF) << 16) | ((q3 & 0xFF) << 24);
      qs += q0 + q1 + q2 + q3;
    }
#pragma unroll
    for (int off = 32; off; off >>= 1) qs += __shfl_xor(qs, off);
    if ((tid & 63) == 0) wq[tid >> 6] = qs;
    __syncthreads();
    if (tid == 0) { maxrow[o] = M; qcsum[o] = wq[0] + wq[1] + wq[2] + wq[3]; }
  }
}

// ---------------- Phase 2: i8 16x16x64 MFMA GEMM, 256^2 phased pipeline ------------
// y_dot[m,n] = sum_k qa[m,k]*qc[n,k].
// Swizzle (T2): LDS slot (row, gs) holds global 16B k-group gg = gs ^ ((row>>1)&3).
//   Staging keeps LDS dest LINEAR in lane (rb*64 + lane*16) per global_load_lds
//   rules; the swizzle is applied on the per-lane GLOBAL source address (inverse)
//   and on the ds_read offset (forward) -- both-sides pattern.
//   Read bank check: start-bank = 16*(lm&1) + 4*(quad^((lm>>1)&3)); 8 distinct
//   16B-aligned starts x 8 lanes, each ds_read_b128 lane covers 4 banks ->
//   256 bank-accesses spread uniformly 8/bank = structural minimum (conflict-free).
// Race-free double-buffer: step t reads slot[t&1]; step t+1 burst-staged at the top
// of step t into slot[(t+1)&1] (readers of that slot finished before the previous
// __syncthreads). The per-step vmcnt(0) drain (inside __syncthreads) waits on loads
// issued a full step (~1300 cyc of MFMA) earlier -> cheap.
__global__ __launch_bounds__(512, 2) void gemm_kernel(
    const char* __restrict__ A, const char* __restrict__ C,
    unsigned short* __restrict__ partials) {
  __shared__ __align__(16) char As[2][BM * BKB];   // 2 x 16 KiB
  __shared__ __align__(16) char Bs[2][BN * BKB];   // 2 x 16 KiB

  // XCD-aware bijective remap: each XCD owns 32 consecutive logical blocks
  const int id = (blockIdx.x & 7) * (GRID_BLOCKS / 8) + (blockIdx.x >> 3);
  const int z  = id >> 6;          // 64 blocks per z-plane
  const int p  = id & 63;
  const int by = p >> 2;           // 16 M-tiles
  const int bx = p & 3;            // 4 N-tiles
  const int bm0 = by * BM;
  const int bn0 = bx * BN;
  const int kt0 = z * KZ;

  const int tid  = threadIdx.x;
  const int wave = tid >> 6;
  const int lane = tid & 63;
  const int quad = lane >> 4;
  const int lm   = lane & 15;
  const int wm   = (wave >> 2) * 128;   // 2 M-wave-groups
  const int wn   = (wave & 3) * 64;     // 4 N-wave-groups

  // staging decode: wave covers rows [wave*32,+32) per operand in 2 rounds of 16;
  // lane -> slot (row = rb+(lane>>2), gs = lane&3); global group gg = gs ^ ((row>>1)&3)
  const int r4 = lane >> 2;
  const int gg = (lane & 3) ^ ((lane >> 3) & 3);   // rb%16==0 -> (row>>1)&3 == (lane>>3)&3

  const char* pA0 = A + (size_t)(bm0 + wave * 32 + r4) * KDIM + kt0 + gg * 16;
  const char* pB0 = C + (size_t)(bn0 + wave * 32 + r4) * KDIM + kt0 + gg * 16;
  const int lo = wave * 32 * BKB;   // wave's LDS base within a slot

  v4i acc[8][4] = {};
  const int kx = (quad ^ ((lm >> 1) & 3)) * 16;   // swizzled ds_read group offset

#define STAGE(sl)                                                        \
  {                                                                      \
    _Pragma("unroll")                                                    \
    for (int j = 0; j < 2; ++j) {                                        \
      gld16(pA0 + (size_t)j * (16 * KDIM), As[sl] + lo + j * (16 * BKB));\
      gld16(pB0 + (size_t)j * (16 * KDIM), Bs[sl] + lo + j * (16 * BKB));\
    }                                                                    \
    pA0 += BKB; pB0 += BKB;                                              \
  }

  // prologue: stage step 0 -> slot 0
  STAGE(0);
  __syncthreads();

  for (int t = 0; t < KSTEPS; ++t) {
    const int cur = t & 1;

    // burst-prefetch step t+1 into the other slot (free since last __syncthreads)
    if (t + 1 < KSTEPS) STAGE(cur ^ 1);

    const char* cA = As[cur];
    const char* cB = Bs[cur];
    v4i a[4], b[4];

    // ---- phase 0: read a(fm0-3) + b(fn0-3); mfma fm0-3 x fn0-3 ----
#pragma unroll
    for (int f = 0; f < 4; ++f)
      a[f] = *(const v4i*)(cA + (wm + f * 16 + lm) * BKB + kx);
#pragma unroll
    for (int f = 0; f < 4; ++f)
      b[f] = *(const v4i*)(cB + (wn + f * 16 + lm) * BKB + kx);
    __builtin_amdgcn_s_barrier();
    __builtin_amdgcn_s_setprio(1);
#pragma unroll
    for (int fm = 0; fm < 4; ++fm)
#pragma unroll
      for (int fn = 0; fn < 4; ++fn)
        acc[fm][fn] = __builtin_amdgcn_mfma_i32_16x16x64_i8(a[fm], b[fn], acc[fm][fn], 0, 0, 0);
    __builtin_amdgcn_s_setprio(0);
    __builtin_amdgcn_s_barrier();

    // ---- phase 1: read a(fm4-7) into same regs; mfma fm4-7 x fn0-3 ----
#pragma unroll
    for (int f = 0; f < 4; ++f)
      a[f] = *(const v4i*)(cA + (wm + (f + 4) * 16 + lm) * BKB + kx);
    __builtin_amdgcn_s_barrier();
    __builtin_amdgcn_s_setprio(1);
#pragma unroll
    for (int fm = 0; fm < 4; ++fm)
#pragma unroll
      for (int fn = 0; fn < 4; ++fn)
        acc[fm + 4][fn] = __builtin_amdgcn_mfma_i32_16x16x64_i8(a[fm], b[fn], acc[fm + 4][fn], 0, 0, 0);
    __builtin_amdgcn_s_setprio(0);

    __syncthreads();   // vmcnt(0) drain of loads issued a full step ago; slot swap
  }
#undef STAGE

  // epilogue: C/D layout (dtype-independent): col = lane&15, row = quad*4 + reg
  unsigned short* out = partials + (size_t)z * BATCH * OUTC;
#pragma unroll
  for (int fm = 0; fm < 8; ++fm) {
    const int row0 = bm0 + wm + fm * 16 + quad * 4;
#pragma unroll
    for (int fn = 0; fn < 4; ++fn) {
      const int col = bn0 + wn + fn * 16 + lm;
#pragma unroll
      for (int r = 0; r < 4; ++r)
        out[(size_t)(row0 + r) * OUTC + col] = f2bf((float)acc[fm][fn][r]);
    }
  }
}

// ---------------- Phase 3: reduce + dequant ----------------
// y[b,o] = M[o]*(Sdot + 127*Qc[o]) / (127*254)
__global__ __launch_bounds__(256) void reduce_kernel(
    const unsigned short* __restrict__ P, const float* __restrict__ maxrow,
    const int* __restrict__ qcsum, float* __restrict__ out) {
  const size_t nel = (size_t)BATCH * OUTC;
  const size_t base = ((size_t)blockIdx.x * 256 + threadIdx.x) * 8;
  float s[8] = {};
#pragma unroll
  for (int t = 0; t < SPLITS; ++t) {
    v8s v = *(const v8s*)(P + t * nel + base);
#pragma unroll
    for (int j = 0; j < 8; ++j) s[j] += bf2f((unsigned short)v[j]);
  }
  const int o0 = (int)(base & (OUTC - 1));
  const float inv = 1.0f / 32258.0f;   // 127*254
#pragma unroll
  for (int j = 0; j < 8; ++j) {
    const float M = maxrow[o0 + j];
    const int   Q = qcsum[o0 + j];
    s[j] = M * (s[j] + 127.0f * (float)Q) * inv;
  }
  *(float4*)(out + base)     = float4{s[0], s[1], s[2], s[3]};
  *(float4*)(out + base + 4) = float4{s[4], s[5], s[6], s[7]};
}

extern "C" void kernel_launch(void* const* d_in, const int* in_sizes, int n_in,
                              void* d_out, int out_size, void* d_ws, size_t ws_size,
                              hipStream_t stream) {
  const float* x       = (const float*)d_in[0];
  const float* coeffs  = (const float*)d_in[1];
  const float* centers = (const float*)d_in[2];
  const float* slopes  = (const float*)d_in[3];
  const float* alpha   = (const float*)d_in[4];
  const float* beta    = (const float*)d_in[5];
  float* out = (float*)d_out;

  const size_t a_bytes    = (size_t)BATCH * KDIM;                 // 32 MiB i8
  const size_t c_bytes    = (size_t)OUTC * KDIM;                  // 8 MiB i8
  const size_t stat_bytes = OUTC * sizeof(float);                 // 4 KiB
  const size_t qcs_bytes  = OUTC * sizeof(int);                   // 4 KiB
  const size_t part_bytes = (size_t)SPLITS * BATCH * OUTC * 2;    // 32 MiB bf16
  if (ws_size < a_bytes + c_bytes + stat_bytes + qcs_bytes + part_bytes) return;

  char*  Ai8    = (char*)d_ws;
  char*  Ci8    = Ai8 + a_bytes;
  float* maxrow = (float*)(Ci8 + c_bytes);
  int*   qcsum  = (int*)((char*)maxrow + stat_bytes);
  unsigned short* parts = (unsigned short*)((char*)qcsum + qcs_bytes);

  prep_kernel<<<PREP_BLOCKS, 256, 0, stream>>>(
      x, (const float4*)coeffs, centers, slopes, alpha, beta,
      Ai8, (int*)Ci8, maxrow, qcsum);

  gemm_kernel<<<GRID_BLOCKS, 512, 0, stream>>>(Ai8, Ci8, parts);

  reduce_kernel<<<(int)((size_t)BATCH * OUTC / 8 / 256), 256, 0, stream>>>(
      parts, maxrow, qcsum, out);
}

// Round 3
// 160.174 us; speedup vs baseline: 1.0253x; 1.0253x over previous
//
#include <hip/hip_runtime.h>
#include <hip/hip_bf16.h>
#include <cstdint>
#include <cstddef>

#define BATCH 4096
#define INC   1024
#define OUTC  1024
#define NB    8
#define KDIM  (INC * NB)   // 8192 (elements == bytes in i8)

// GEMM tile: 256x256 block, BK=64 bytes i8, 8 waves (2M x 4N), wave tile 128x64
// (8x4 frags of 16x16x64 i8). TRIPLE-buffered STATIC LDS (3 x 32 KiB = 96 KiB),
// prefetch depth 2 with COUNTED s_waitcnt vmcnt(8) at step entry (T4) -- never a
// full drain in the main loop. All 12 ds_reads issued before the first MFMA
// cluster; lgkmcnt(4)/lgkmcnt(0) split so the second operand set completes under
// the first 16-MFMA cluster (T3). setprio around MFMA clusters (T5).
// XOR-swizzled 16B k-groups (T2), bijective XCD swizzle (T1).
#define BM 256
#define BN 256
#define BKB 64                  // k-bytes per step
#define SPLITS 4
#define KZ (KDIM / SPLITS)      // 2048 bytes per z
#define KSTEPS (KZ / BKB)       // 32 even steps, no tail
#define GRID_BLOCKS ((OUTC / BN) * (BATCH / BM) * SPLITS)   // 4*16*4 = 256 = 1 block/CU

// prep dispatch partition: expand | fused rowmax+quant (one block per coeff row)
#define EXPAND_BLOCKS  ((BATCH * INC) / 256)   // 16384
#define QUANT_BLOCKS   OUTC                    // 1024
#define PREP_BLOCKS    (EXPAND_BLOCKS + QUANT_BLOCKS)

typedef int   v4i __attribute__((ext_vector_type(4)));
typedef char  v8c __attribute__((ext_vector_type(8)));
typedef short v8s __attribute__((ext_vector_type(8)));

__device__ __forceinline__ unsigned short f2bf(float f) {
  union { float f; unsigned u; } v; v.f = f;
  unsigned r = v.u + 0x7fffu + ((v.u >> 16) & 1u);  // round-to-nearest-even
  return (unsigned short)(r >> 16);
}
__device__ __forceinline__ float bf2f(unsigned short h) {
  union { unsigned u; float f; } v; v.u = ((unsigned)h) << 16; return v.f;
}

// async 16B global -> LDS (DMA; LDS dest = wave-uniform base + lane*16)
__device__ __forceinline__ void gld16(const char* g, char* l) {
  __builtin_amdgcn_global_load_lds(
      (const __attribute__((address_space(1))) unsigned int*)g,
      (__attribute__((address_space(3))) unsigned int*)l, 16, 0, 0);
}

// ---------------- Phase 1 (fused dispatch): expand basis | rowmax+quantize coeffs -------
__global__ __launch_bounds__(256) void prep_kernel(
    const float* __restrict__ x, const float4* __restrict__ coeffs4,
    const float* __restrict__ centers, const float* __restrict__ slopes,
    const float* __restrict__ alpha, const float* __restrict__ beta,
    char* __restrict__ Ai8, int* __restrict__ Ci8i,
    float* __restrict__ maxrow, int* __restrict__ qcsum) {
  const int blk = blockIdx.x;
  const int tid = threadIdx.x;
  if (blk < EXPAND_BLOCKS) {
    const int idx = blk * 256 + tid;          // (b,i) pair
    const int i = idx & (INC - 1);
    const float u = alpha[i] * x[idx] + beta[i];
    const float s0 = slopes[i * NB];
    const float c0 = centers[i * NB];
    const float c1 = centers[i * NB + 1];
    const float L2E2 = 2.8853900817779268f;   // 2*log2(e)
    const float a2 = L2E2 * s0;
    float e = __builtin_amdgcn_exp2f(a2 * (c0 - u));   // inf -> rcp -> 0: correct limit
    const float R = __builtin_amdgcn_exp2f(a2 * (c1 - c0));
    v8c q;
#pragma unroll
    for (int m = 0; m < 8; ++m) {
      float basis = __builtin_amdgcn_rcpf(1.0f + e);
      q[m] = (char)(int)rintf(basis * 254.0f - 127.0f);
      e *= R;
    }
    *(v8c*)(Ai8 + (size_t)idx * 8) = q;   // 8B coalesced store
  } else {
    const int o = blk - EXPAND_BLOCKS;
    const float4* row = coeffs4 + (size_t)o * (KDIM / 4);
    float4 v[8];
    float m = 0.0f;
#pragma unroll
    for (int j = 0; j < 8; ++j) {
      v[j] = row[tid + 256 * j];
      m = fmaxf(m, fmaxf(fmaxf(fabsf(v[j].x), fabsf(v[j].y)),
                         fmaxf(fabsf(v[j].z), fabsf(v[j].w))));
    }
#pragma unroll
    for (int off = 32; off; off >>= 1) m = fmaxf(m, __shfl_xor(m, off));
    __shared__ float wm[4];
    __shared__ int   wq[4];
    if ((tid & 63) == 0) wm[tid >> 6] = m;
    __syncthreads();
    const float M = fmaxf(fmaxf(fmaxf(wm[0], wm[1]), fmaxf(wm[2], wm[3])), 1e-30f);
    const float s = 127.0f / M;
    int qs = 0;
#pragma unroll
    for (int j = 0; j < 8; ++j) {
      int q0 = (int)rintf(v[j].x * s), q1 = (int)rintf(v[j].y * s);
      int q2 = (int)rintf(v[j].z * s), q3 = (int)rintf(v[j].w * s);
      Ci8i[(size_t)o * (KDIM / 4) + tid + 256 * j] =
          (q0 & 0xFF) | ((q1 & 0xFF) << 8) | ((q2 & 0xFF) << 16) | ((q3 & 0xFF) << 24);
      qs += q0 + q1 + q2 + q3;
    }
#pragma unroll
    for (int off = 32; off; off >>= 1) qs += __shfl_xor(qs, off);
    if ((tid & 63) == 0) wq[tid >> 6] = qs;
    __syncthreads();
    if (tid == 0) { maxrow[o] = M; qcsum[o] = wq[0] + wq[1] + wq[2] + wq[3]; }
  }
}

// ---------------- Phase 2: i8 16x16x64 MFMA GEMM, counted-vmcnt pipeline ------------
// y_dot[m,n] = sum_k qa[m,k]*qc[n,k].
// Swizzle (T2, verified R2): LDS slot (row, gs) holds global 16B k-group
// gg = gs ^ ((row>>1)&3); staging LDS dest LINEAR in lane (global_load_lds rule);
// inverse swizzle on per-lane global source, forward swizzle on ds_read offset.
// Pipeline (T3+T4): 3 slots, prefetch depth 2. Step t:
//   vmcnt(8)  -> own batch-t loads (4 gld16) landed; t+1,t+2 in flight
//   s_barrier -> everyone's batch-t landed: slot[t%3] complete
//   issue 12 ds_read_b128 (a0-3, b0-3, a4-7)
//   lgkmcnt(4)  -> a0-3,b0-3 ready; a4-7 complete UNDER first MFMA cluster
//   16 MFMA (setprio) ; lgkmcnt(0) ; 16 MFMA (setprio)
//   s_barrier -> all waves done reading slot[t%3]
//   STAGE batch t+3 into slot[t%3]  (WAR-safe after barrier)
// Never vmcnt(0) in the main loop; tails use vmcnt(4)/vmcnt(0).
__global__ __launch_bounds__(512, 2) void gemm_kernel(
    const char* __restrict__ A, const char* __restrict__ C,
    unsigned short* __restrict__ partials) {
  __shared__ __align__(16) char As[3][BM * BKB];   // 3 x 16 KiB
  __shared__ __align__(16) char Bs[3][BN * BKB];   // 3 x 16 KiB

  // XCD-aware bijective remap: each XCD owns 32 consecutive logical blocks
  const int id = (blockIdx.x & 7) * (GRID_BLOCKS / 8) + (blockIdx.x >> 3);
  const int z  = id >> 6;          // 64 blocks per z-plane
  const int p  = id & 63;
  const int by = p >> 2;           // 16 M-tiles
  const int bx = p & 3;            // 4 N-tiles
  const int bm0 = by * BM;
  const int bn0 = bx * BN;
  const int kt0 = z * KZ;

  const int tid  = threadIdx.x;
  const int wave = tid >> 6;
  const int lane = tid & 63;
  const int quad = lane >> 4;
  const int lm   = lane & 15;
  const int wm   = (wave >> 2) * 128;   // 2 M-wave-groups
  const int wn   = (wave & 3) * 64;     // 4 N-wave-groups

  // staging decode: wave covers rows [wave*32,+32) per operand in 2 rounds of 16;
  // lane -> slot (row = rb+(lane>>2), gs = lane&3); global group gg = gs^((row>>1)&3)
  const int r4 = lane >> 2;
  const int gg = (lane & 3) ^ ((lane >> 3) & 3);

  const char* pA0 = A + (size_t)(bm0 + wave * 32 + r4) * KDIM + kt0 + gg * 16;
  const char* pB0 = C + (size_t)(bn0 + wave * 32 + r4) * KDIM + kt0 + gg * 16;
  const int lo = wave * 32 * BKB;   // wave's LDS base within a slot

  v4i acc[8][4] = {};
  const int kx = (quad ^ ((lm >> 1) & 3)) * 16;   // swizzled ds_read group offset

  static_assert(KSTEPS >= 3 && (KSTEPS - 2) % 1 == 0, "pipeline needs >=3 steps");

#define STAGE(SL)                                                            \
  {                                                                          \
    _Pragma("unroll")                                                        \
    for (int j = 0; j < 2; ++j) {                                            \
      gld16(pA0 + (size_t)j * (16 * KDIM), As[SL] + lo + j * (16 * BKB));    \
      gld16(pB0 + (size_t)j * (16 * KDIM), Bs[SL] + lo + j * (16 * BKB));    \
    }                                                                        \
    pA0 += BKB; pB0 += BKB;                                                  \
  }

#define STEP(SL, VMSTR, DOSTAGE)                                             \
  {                                                                          \
    asm volatile("s_waitcnt vmcnt(" VMSTR ")" ::: "memory");                 \
    __builtin_amdgcn_sched_barrier(0);                                       \
    __builtin_amdgcn_s_barrier();                                            \
    const char* cA = As[SL];                                                 \
    const char* cB = Bs[SL];                                                 \
    v4i a[4], b[4], a2[4];                                                   \
    _Pragma("unroll")                                                        \
    for (int f = 0; f < 4; ++f)                                              \
      a[f] = *(const v4i*)(cA + (wm + f * 16 + lm) * BKB + kx);              \
    _Pragma("unroll")                                                        \
    for (int f = 0; f < 4; ++f)                                              \
      b[f] = *(const v4i*)(cB + (wn + f * 16 + lm) * BKB + kx);              \
    _Pragma("unroll")                                                        \
    for (int f = 0; f < 4; ++f)                                              \
      a2[f] = *(const v4i*)(cA + (wm + (f + 4) * 16 + lm) * BKB + kx);       \
    asm volatile("s_waitcnt lgkmcnt(4)" ::: "memory");                       \
    __builtin_amdgcn_sched_barrier(0);                                       \
    __builtin_amdgcn_s_setprio(1);                                           \
    _Pragma("unroll")                                                        \
    for (int fm = 0; fm < 4; ++fm)                                           \
      _Pragma("unroll")                                                      \
      for (int fn = 0; fn < 4; ++fn)                                         \
        acc[fm][fn] = __builtin_amdgcn_mfma_i32_16x16x64_i8(a[fm], b[fn], acc[fm][fn], 0, 0, 0); \
    __builtin_amdgcn_s_setprio(0);                                           \
    asm volatile("s_waitcnt lgkmcnt(0)" ::: "memory");                       \
    __builtin_amdgcn_sched_barrier(0);                                       \
    __builtin_amdgcn_s_setprio(1);                                           \
    _Pragma("unroll")                                                        \
    for (int fm = 0; fm < 4; ++fm)                                           \
      _Pragma("unroll")                                                      \
      for (int fn = 0; fn < 4; ++fn)                                         \
        acc[fm + 4][fn] = __builtin_amdgcn_mfma_i32_16x16x64_i8(a2[fm], b[fn], acc[fm + 4][fn], 0, 0, 0); \
    __builtin_amdgcn_s_setprio(0);                                           \
    __builtin_amdgcn_s_barrier();                                            \
    if (DOSTAGE) STAGE(SL);                                                  \
  }

  // prologue: stage batches 0,1,2 -> slots 0,1,2 (12 loads in flight)
  STAGE(0);
  STAGE(1);
  STAGE(2);

  // main loop: gate vmcnt(8) = batches t+1,t+2 outstanding after batch t lands
  for (int t = 0; t < KSTEPS - 2; ++t) {
    const int sl = t % 3;
    STEP(sl, "8", (t < KSTEPS - 3));
  }
  // tails: fewer batches outstanding
  STEP((KSTEPS - 2) % 3, "4", false);
  STEP((KSTEPS - 1) % 3, "0", false);
#undef STEP
#undef STAGE

  // epilogue: C/D layout (dtype-independent): col = lane&15, row = quad*4 + reg
  unsigned short* out = partials + (size_t)z * BATCH * OUTC;
#pragma unroll
  for (int fm = 0; fm < 8; ++fm) {
    const int row0 = bm0 + wm + fm * 16 + quad * 4;
#pragma unroll
    for (int fn = 0; fn < 4; ++fn) {
      const int col = bn0 + wn + fn * 16 + lm;
#pragma unroll
      for (int r = 0; r < 4; ++r)
        out[(size_t)(row0 + r) * OUTC + col] = f2bf((float)acc[fm][fn][r]);
    }
  }
}

// ---------------- Phase 3: reduce + dequant ----------------
// y[b,o] = M[o]*(Sdot + 127*Qc[o]) / (127*254)
__global__ __launch_bounds__(256) void reduce_kernel(
    const unsigned short* __restrict__ P, const float* __restrict__ maxrow,
    const int* __restrict__ qcsum, float* __restrict__ out) {
  const size_t nel = (size_t)BATCH * OUTC;
  const size_t base = ((size_t)blockIdx.x * 256 + threadIdx.x) * 8;
  float s[8] = {};
#pragma unroll
  for (int t = 0; t < SPLITS; ++t) {
    v8s v = *(const v8s*)(P + t * nel + base);
#pragma unroll
    for (int j = 0; j < 8; ++j) s[j] += bf2f((unsigned short)v[j]);
  }
  const int o0 = (int)(base & (OUTC - 1));
  const float inv = 1.0f / 32258.0f;   // 127*254
#pragma unroll
  for (int j = 0; j < 8; ++j) {
    const float M = maxrow[o0 + j];
    const int   Q = qcsum[o0 + j];
    s[j] = M * (s[j] + 127.0f * (float)Q) * inv;
  }
  *(float4*)(out + base)     = float4{s[0], s[1], s[2], s[3]};
  *(float4*)(out + base + 4) = float4{s[4], s[5], s[6], s[7]};
}

extern "C" void kernel_launch(void* const* d_in, const int* in_sizes, int n_in,
                              void* d_out, int out_size, void* d_ws, size_t ws_size,
                              hipStream_t stream) {
  const float* x       = (const float*)d_in[0];
  const float* coeffs  = (const float*)d_in[1];
  const float* centers = (const float*)d_in[2];
  const float* slopes  = (const float*)d_in[3];
  const float* alpha   = (const float*)d_in[4];
  const float* beta    = (const float*)d_in[5];
  float* out = (float*)d_out;

  const size_t a_bytes    = (size_t)BATCH * KDIM;                 // 32 MiB i8
  const size_t c_bytes    = (size_t)OUTC * KDIM;                  // 8 MiB i8
  const size_t stat_bytes = OUTC * sizeof(float);                 // 4 KiB
  const size_t qcs_bytes  = OUTC * sizeof(int);                   // 4 KiB
  const size_t part_bytes = (size_t)SPLITS * BATCH * OUTC * 2;    // 32 MiB bf16
  if (ws_size < a_bytes + c_bytes + stat_bytes + qcs_bytes + part_bytes) return;

  char*  Ai8    = (char*)d_ws;
  char*  Ci8    = Ai8 + a_bytes;
  float* maxrow = (float*)(Ci8 + c_bytes);
  int*   qcsum  = (int*)((char*)maxrow + stat_bytes);
  unsigned short* parts = (unsigned short*)((char*)qcsum + qcs_bytes);

  prep_kernel<<<PREP_BLOCKS, 256, 0, stream>>>(
      x, (const float4*)coeffs, centers, slopes, alpha, beta,
      Ai8, (int*)Ci8, maxrow, qcsum);

  gemm_kernel<<<GRID_BLOCKS, 512, 0, stream>>>(Ai8, Ci8, parts);

  reduce_kernel<<<(int)((size_t)BATCH * OUTC / 8 / 256), 256, 0, stream>>>(
      parts, maxrow, qcsum, out);
}

// Round 5
// 152.806 us; speedup vs baseline: 1.0747x; 1.0482x over previous
//
#include <hip/hip_runtime.h>
#include <hip/hip_bf16.h>
#include <cstdint>
#include <cstddef>

#define BATCH 4096
#define INC   1024
#define OUTC  1024
#define NB    8
#define KDIM  (INC * NB)   // 8192 (elements == bytes in i8)

// GEMM tile: 256x256 block, BK=64 bytes i8, 8 waves (2M x 4N), wave tile 128x64
// (8x4 frags of 16x16x64 i8). TRIPLE-buffered STATIC LDS (3 x 32 KiB = 96 KiB),
// prefetch depth 2, COUNTED vmcnt(4) gates (T4), and REGISTER-LEVEL operand
// double-buffering: step t issues the 12 ds_read_b128 for batch t+1 BEFORE the
// MFMA cluster for batch t, so the LDS port (~1150 cyc/step) is serviced under
// the MFMA (~1300 cyc/step) instead of serializing with it (the R3 stall).
// lgkmcnt(12) gates only the OLD reads (in-order DS completion). setprio (T5),
// XOR-swizzle (T2), bijective XCD swizzle (T1).
#define BM 256
#define BN 256
#define BKB 64                  // k-bytes per step
#define SPLITS 4
#define KZ (KDIM / SPLITS)      // 2048 bytes per z
#define KSTEPS (KZ / BKB)       // 32 even steps, no tail
#define GRID_BLOCKS ((OUTC / BN) * (BATCH / BM) * SPLITS)   // 4*16*4 = 256 = 1 block/CU

// prep dispatch partition: expand | fused rowmax+quant (one block per coeff row)
#define EXPAND_BLOCKS  ((BATCH * INC) / 256)   // 16384
#define QUANT_BLOCKS   OUTC                    // 1024
#define PREP_BLOCKS    (EXPAND_BLOCKS + QUANT_BLOCKS)

typedef int   v4i __attribute__((ext_vector_type(4)));
typedef char  v8c __attribute__((ext_vector_type(8)));
typedef short v8s __attribute__((ext_vector_type(8)));

__device__ __forceinline__ unsigned short f2bf(float f) {
  union { float f; unsigned u; } v; v.f = f;
  unsigned r = v.u + 0x7fffu + ((v.u >> 16) & 1u);  // round-to-nearest-even
  return (unsigned short)(r >> 16);
}
__device__ __forceinline__ float bf2f(unsigned short h) {
  union { unsigned u; float f; } v; v.u = ((unsigned)h) << 16; return v.f;
}

// async 16B global -> LDS (DMA; LDS dest = wave-uniform base + lane*16)
__device__ __forceinline__ void gld16(const char* g, char* l) {
  __builtin_amdgcn_global_load_lds(
      (const __attribute__((address_space(1))) unsigned int*)g,
      (__attribute__((address_space(3))) unsigned int*)l, 16, 0, 0);
}

// ---------------- Phase 1 (fused dispatch): expand basis | rowmax+quantize coeffs -------
__global__ __launch_bounds__(256) void prep_kernel(
    const float* __restrict__ x, const float4* __restrict__ coeffs4,
    const float* __restrict__ centers, const float* __restrict__ slopes,
    const float* __restrict__ alpha, const float* __restrict__ beta,
    char* __restrict__ Ai8, int* __restrict__ Ci8i,
    float* __restrict__ maxrow, int* __restrict__ qcsum) {
  const int blk = blockIdx.x;
  const int tid = threadIdx.x;
  if (blk < EXPAND_BLOCKS) {
    const int idx = blk * 256 + tid;          // (b,i) pair
    const int i = idx & (INC - 1);
    const float u = alpha[i] * x[idx] + beta[i];
    const float s0 = slopes[i * NB];
    const float c0 = centers[i * NB];
    const float c1 = centers[i * NB + 1];
    const float L2E2 = 2.8853900817779268f;   // 2*log2(e)
    const float a2 = L2E2 * s0;
    float e = __builtin_amdgcn_exp2f(a2 * (c0 - u));   // inf -> rcp -> 0: correct limit
    const float R = __builtin_amdgcn_exp2f(a2 * (c1 - c0));
    v8c q;
#pragma unroll
    for (int m = 0; m < 8; ++m) {
      float basis = __builtin_amdgcn_rcpf(1.0f + e);
      q[m] = (char)(int)rintf(basis * 254.0f - 127.0f);
      e *= R;
    }
    *(v8c*)(Ai8 + (size_t)idx * 8) = q;   // 8B coalesced store
  } else {
    const int o = blk - EXPAND_BLOCKS;
    const float4* row = coeffs4 + (size_t)o * (KDIM / 4);
    float4 v[8];
    float m = 0.0f;
#pragma unroll
    for (int j = 0; j < 8; ++j) {
      v[j] = row[tid + 256 * j];
      m = fmaxf(m, fmaxf(fmaxf(fabsf(v[j].x), fabsf(v[j].y)),
                         fmaxf(fabsf(v[j].z), fabsf(v[j].w))));
    }
#pragma unroll
    for (int off = 32; off; off >>= 1) m = fmaxf(m, __shfl_xor(m, off));
    __shared__ float wm[4];
    __shared__ int   wq[4];
    if ((tid & 63) == 0) wm[tid >> 6] = m;
    __syncthreads();
    const float M = fmaxf(fmaxf(fmaxf(wm[0], wm[1]), fmaxf(wm[2], wm[3])), 1e-30f);
    const float s = 127.0f / M;
    int qs = 0;
#pragma unroll
    for (int j = 0; j < 8; ++j) {
      int q0 = (int)rintf(v[j].x * s), q1 = (int)rintf(v[j].y * s);
      int q2 = (int)rintf(v[j].z * s), q3 = (int)rintf(v[j].w * s);
      Ci8i[(size_t)o * (KDIM / 4) + tid + 256 * j] =
          (q0 & 0xFF) | ((q1 & 0xFF) << 8) | ((q2 & 0xFF) << 16) | ((q3 & 0xFF) << 24);
      qs += q0 + q1 + q2 + q3;
    }
#pragma unroll
    for (int off = 32; off; off >>= 1) qs += __shfl_xor(qs, off);
    if ((tid & 63) == 0) wq[tid >> 6] = qs;
    __syncthreads();
    if (tid == 0) { maxrow[o] = M; qcsum[o] = wq[0] + wq[1] + wq[2] + wq[3]; }
  }
}

// ---------------- Phase 2: i8 16x16x64 MFMA GEMM, read-ahead pipeline ------------
// Swizzle (T2, verified R2/R3): LDS slot (row, gs) holds global 16B k-group
// gg = gs ^ ((row>>1)&3); staging LDS dest LINEAR in lane; inverse swizzle on the
// per-lane global source, forward swizzle on the ds_read offset.
// Pipeline invariants (batch k lives in slot k%3):
//   - MFMA(t) consumes registers loaded during step t-1.
//   - Step t issues ds_reads for batch t+1 (slot (t+1)%3) BEFORE MFMA(t).
//   - vmcnt(4) at step t top: batch t+1 DMA landed (only batch t+2 outstanding);
//     barrier makes it block-wide.
//   - lgkmcnt(12): DS ops complete in order per wave -> the 12 old (batch t)
//     reads are done; the 12 new (batch t+1) stay in flight under MFMA(t).
//   - barrier after lgkm gate = all waves' batch-t reads COMPLETE -> staging
//     batch t+3 into slot t%3 is WAR-safe.
// Never vmcnt(0) in steady state; barriers 2/step.
__global__ __launch_bounds__(512, 2) void gemm_kernel(
    const char* __restrict__ A, const char* __restrict__ C,
    unsigned short* __restrict__ partials) {
  __shared__ __align__(16) char As[3][BM * BKB];   // 3 x 16 KiB
  __shared__ __align__(16) char Bs[3][BN * BKB];   // 3 x 16 KiB

  // XCD-aware bijective remap: each XCD owns 32 consecutive logical blocks
  const int id = (blockIdx.x & 7) * (GRID_BLOCKS / 8) + (blockIdx.x >> 3);
  const int z  = id >> 6;          // 64 blocks per z-plane
  const int p  = id & 63;
  const int by = p >> 2;           // 16 M-tiles
  const int bx = p & 3;            // 4 N-tiles
  const int bm0 = by * BM;
  const int bn0 = bx * BN;
  const int kt0 = z * KZ;

  const int tid  = threadIdx.x;
  const int wave = tid >> 6;
  const int lane = tid & 63;
  const int quad = lane >> 4;
  const int lm   = lane & 15;
  const int wm   = (wave >> 2) * 128;   // 2 M-wave-groups
  const int wn   = (wave & 3) * 64;     // 4 N-wave-groups

  // staging decode (unchanged): lane -> slot (row = rb+(lane>>2), gs = lane&3);
  // global group gg = gs ^ ((row>>1)&3)
  const int r4 = lane >> 2;
  const int gg = (lane & 3) ^ ((lane >> 3) & 3);

  const char* pA0 = A + (size_t)(bm0 + wave * 32 + r4) * KDIM + kt0 + gg * 16;
  const char* pB0 = C + (size_t)(bn0 + wave * 32 + r4) * KDIM + kt0 + gg * 16;
  const int lo = wave * 32 * BKB;   // wave's LDS base within a slot

  const int kx   = (quad ^ ((lm >> 1) & 3)) * 16;   // swizzled ds_read group offset
  const int aoff = (wm + lm) * BKB + kx;            // + f*1024 per fragment
  const int boff = (wn + lm) * BKB + kx;

  v4i acc[8][4] = {};
  v4i a0v[8], b0v[4], a1v[8], b1v[4];   // two named operand sets (no dyn indexing)
  int srd = 0;   // slot of next batch to ds_read
  int sst = 0;   // slot of next batch to stage

#define STAGE_NEXT()                                                         \
  {                                                                          \
    _Pragma("unroll")                                                        \
    for (int j = 0; j < 2; ++j) {                                            \
      gld16(pA0 + (size_t)j * (16 * KDIM), As[sst] + lo + j * (16 * BKB));   \
      gld16(pB0 + (size_t)j * (16 * KDIM), Bs[sst] + lo + j * (16 * BKB));   \
    }                                                                        \
    pA0 += BKB; pB0 += BKB;                                                  \
    sst = (sst == 2) ? 0 : sst + 1;                                          \
  }

#define READS(AV, BV)                                                        \
  {                                                                          \
    const char* cA = As[srd] + aoff;                                         \
    const char* cB = Bs[srd] + boff;                                         \
    _Pragma("unroll")                                                        \
    for (int f = 0; f < 8; ++f) AV[f] = *(const v4i*)(cA + f * 16 * BKB);    \
    _Pragma("unroll")                                                        \
    for (int f = 0; f < 4; ++f) BV[f] = *(const v4i*)(cB + f * 16 * BKB);    \
    srd = (srd == 2) ? 0 : srd + 1;                                          \
  }

#define MFMA32(AV, BV)                                                       \
  {                                                                          \
    __builtin_amdgcn_s_setprio(1);                                           \
    _Pragma("unroll")                                                        \
    for (int fm = 0; fm < 8; ++fm)                                           \
      _Pragma("unroll")                                                      \
      for (int fn = 0; fn < 4; ++fn)                                         \
        acc[fm][fn] = __builtin_amdgcn_mfma_i32_16x16x64_i8(AV[fm], BV[fn], acc[fm][fn], 0, 0, 0); \
    __builtin_amdgcn_s_setprio(0);                                           \
  }

  // STEP(t): CUR regs hold batch t; NXT regs receive batch t+1.
#define STEP(CA, CB, NA, NBV, VMS, LGS, DOREADS, DOSTAGE)                    \
  {                                                                          \
    if (DOREADS) {                                                           \
      asm volatile("s_waitcnt vmcnt(" VMS ")" ::: "memory");                 \
      __builtin_amdgcn_sched_barrier(0);                                     \
      __builtin_amdgcn_s_barrier();                                          \
      READS(NA, NBV);                                                        \
    }                                                                        \
    asm volatile("s_waitcnt lgkmcnt(" LGS ")" ::: "memory");                 \
    __builtin_amdgcn_sched_barrier(0);                                       \
    __builtin_amdgcn_s_barrier();                                            \
    if (DOSTAGE) STAGE_NEXT();                                               \
    MFMA32(CA, CB);                                                          \
  }

  // prologue: stage batches 0,1,2 -> slots 0,1,2; read batch 0 into set0
  STAGE_NEXT(); STAGE_NEXT(); STAGE_NEXT();
  asm volatile("s_waitcnt vmcnt(8)" ::: "memory");   // batch 0 landed
  __builtin_amdgcn_sched_barrier(0);
  __builtin_amdgcn_s_barrier();
  READS(a0v, b0v);

  // steady state: t = 0..27 (14 double-steps)
  for (int i = 0; i < 14; ++i) {
    STEP(a0v, b0v, a1v, b1v, "4", "12", true, true);    // even t
    STEP(a1v, b1v, a0v, b0v, "4", "12", true, true);    // odd t
  }
  // tail: t = 28..31
  STEP(a0v, b0v, a1v, b1v, "4", "12", true, true);    // t=28 (stages batch 31)
  STEP(a1v, b1v, a0v, b0v, "4", "12", true, false);   // t=29
  STEP(a0v, b0v, a1v, b1v, "0", "12", true, false);   // t=30
  STEP(a1v, b1v, a0v, b0v, "0", "0",  false, false);  // t=31
#undef STEP
#undef MFMA32
#undef READS
#undef STAGE_NEXT

  // epilogue: C/D layout (dtype-independent): col = lane&15, row = quad*4 + reg
  unsigned short* out = partials + (size_t)z * BATCH * OUTC;
#pragma unroll
  for (int fm = 0; fm < 8; ++fm) {
    const int row0 = bm0 + wm + fm * 16 + quad * 4;
#pragma unroll
    for (int fn = 0; fn < 4; ++fn) {
      const int col = bn0 + wn + fn * 16 + lm;
#pragma unroll
      for (int r = 0; r < 4; ++r)
        out[(size_t)(row0 + r) * OUTC + col] = f2bf((float)acc[fm][fn][r]);
    }
  }
}

// ---------------- Phase 3: reduce + dequant ----------------
// y[b,o] = M[o]*(Sdot + 127*Qc[o]) / (127*254)
__global__ __launch_bounds__(256) void reduce_kernel(
    const unsigned short* __restrict__ P, const float* __restrict__ maxrow,
    const int* __restrict__ qcsum, float* __restrict__ out) {
  const size_t nel = (size_t)BATCH * OUTC;
  const size_t base = ((size_t)blockIdx.x * 256 + threadIdx.x) * 8;
  float s[8] = {};
#pragma unroll
  for (int t = 0; t < SPLITS; ++t) {
    v8s v = *(const v8s*)(P + t * nel + base);
#pragma unroll
    for (int j = 0; j < 8; ++j) s[j] += bf2f((unsigned short)v[j]);
  }
  const int o0 = (int)(base & (OUTC - 1));
  const float inv = 1.0f / 32258.0f;   // 127*254
#pragma unroll
  for (int j = 0; j < 8; ++j) {
    const float M = maxrow[o0 + j];
    const int   Q = qcsum[o0 + j];
    s[j] = M * (s[j] + 127.0f * (float)Q) * inv;
  }
  *(float4*)(out + base)     = float4{s[0], s[1], s[2], s[3]};
  *(float4*)(out + base + 4) = float4{s[4], s[5], s[6], s[7]};
}

extern "C" void kernel_launch(void* const* d_in, const int* in_sizes, int n_in,
                              void* d_out, int out_size, void* d_ws, size_t ws_size,
                              hipStream_t stream) {
  const float* x       = (const float*)d_in[0];
  const float* coeffs  = (const float*)d_in[1];
  const float* centers = (const float*)d_in[2];
  const float* slopes  = (const float*)d_in[3];
  const float* alpha   = (const float*)d_in[4];
  const float* beta    = (const float*)d_in[5];
  float* out = (float*)d_out;

  const size_t a_bytes    = (size_t)BATCH * KDIM;                 // 32 MiB i8
  const size_t c_bytes    = (size_t)OUTC * KDIM;                  // 8 MiB i8
  const size_t stat_bytes = OUTC * sizeof(float);                 // 4 KiB
  const size_t qcs_bytes  = OUTC * sizeof(int);                   // 4 KiB
  const size_t part_bytes = (size_t)SPLITS * BATCH * OUTC * 2;    // 32 MiB bf16
  if (ws_size < a_bytes + c_bytes + stat_bytes + qcs_bytes + part_bytes) return;

  char*  Ai8    = (char*)d_ws;
  char*  Ci8    = Ai8 + a_bytes;
  float* maxrow = (float*)(Ci8 + c_bytes);
  int*   qcsum  = (int*)((char*)maxrow + stat_bytes);
  unsigned short* parts = (unsigned short*)((char*)qcsum + qcs_bytes);

  prep_kernel<<<PREP_BLOCKS, 256, 0, stream>>>(
      x, (const float4*)coeffs, centers, slopes, alpha, beta,
      Ai8, (int*)Ci8, maxrow, qcsum);

  gemm_kernel<<<GRID_BLOCKS, 512, 0, stream>>>(Ai8, Ci8, parts);

  reduce_kernel<<<(int)((size_t)BATCH * OUTC / 8 / 256), 256, 0, stream>>>(
      parts, maxrow, qcsum, out);
}

// Round 6
// 151.738 us; speedup vs baseline: 1.0823x; 1.0070x over previous
//
#include <hip/hip_runtime.h>
#include <hip/hip_bf16.h>
#include <cstdint>
#include <cstddef>

#define BATCH 4096
#define INC   1024
#define OUTC  1024
#define NB    8
#define KDIM  (INC * NB)   // 8192 (elements == bytes in i8)

// GEMM tile: 256(M) x 128(N), BK=64 bytes i8, 8 waves (4M x 2N), wave tile 64x64
// (4x4 frags of 16x16x64 i8, acc = 64 VGPR). Double-buffered LDS (2 x 24 KiB =
// 48 KiB) -> 2 blocks/CU, 4 waves/SIMD: inter-block TLP does the ds_read/MFMA
// overlap (m114) that the 1-block/CU lockstep schedule could not (R2/R3/R5).
// Counted vmcnt(3) (T4), setprio (T5, blocks genuinely desynced now),
// XOR-swizzle (T2, verified R2/R3/R5), bijective XCD swizzle (T1).
#define BM 256
#define BN 128
#define BKB 64                  // k-bytes per step
#define SPLITS 4
#define KZ (KDIM / SPLITS)      // 2048 bytes per z
#define KSTEPS (KZ / BKB)       // 32 even steps, no tail
#define GRID_BLOCKS ((OUTC / BN) * (BATCH / BM) * SPLITS)   // 8*16*4 = 512 = 2 blocks/CU

// prep dispatch partition: expand | fused rowmax+quant (one block per coeff row)
#define EXPAND_BLOCKS  ((BATCH * INC) / 256)   // 16384
#define QUANT_BLOCKS   OUTC                    // 1024
#define PREP_BLOCKS    (EXPAND_BLOCKS + QUANT_BLOCKS)

typedef int   v4i __attribute__((ext_vector_type(4)));
typedef char  v8c __attribute__((ext_vector_type(8)));
typedef short v8s __attribute__((ext_vector_type(8)));

__device__ __forceinline__ unsigned short f2bf(float f) {
  union { float f; unsigned u; } v; v.f = f;
  unsigned r = v.u + 0x7fffu + ((v.u >> 16) & 1u);  // round-to-nearest-even
  return (unsigned short)(r >> 16);
}
__device__ __forceinline__ float bf2f(unsigned short h) {
  union { unsigned u; float f; } v; v.u = ((unsigned)h) << 16; return v.f;
}

// async 16B global -> LDS (DMA; LDS dest = wave-uniform base + lane*16)
__device__ __forceinline__ void gld16(const char* g, char* l) {
  __builtin_amdgcn_global_load_lds(
      (const __attribute__((address_space(1))) unsigned int*)g,
      (__attribute__((address_space(3))) unsigned int*)l, 16, 0, 0);
}

// ---------------- Phase 1 (fused dispatch): expand basis | rowmax+quantize coeffs -------
__global__ __launch_bounds__(256) void prep_kernel(
    const float* __restrict__ x, const float4* __restrict__ coeffs4,
    const float* __restrict__ centers, const float* __restrict__ slopes,
    const float* __restrict__ alpha, const float* __restrict__ beta,
    char* __restrict__ Ai8, int* __restrict__ Ci8i,
    float* __restrict__ maxrow, int* __restrict__ qcsum) {
  const int blk = blockIdx.x;
  const int tid = threadIdx.x;
  if (blk < EXPAND_BLOCKS) {
    const int idx = blk * 256 + tid;          // (b,i) pair
    const int i = idx & (INC - 1);
    const float u = alpha[i] * x[idx] + beta[i];
    const float s0 = slopes[i * NB];
    const float c0 = centers[i * NB];
    const float c1 = centers[i * NB + 1];
    const float L2E2 = 2.8853900817779268f;   // 2*log2(e)
    const float a2 = L2E2 * s0;
    float e = __builtin_amdgcn_exp2f(a2 * (c0 - u));   // inf -> rcp -> 0: correct limit
    const float R = __builtin_amdgcn_exp2f(a2 * (c1 - c0));
    v8c q;
#pragma unroll
    for (int m = 0; m < 8; ++m) {
      float basis = __builtin_amdgcn_rcpf(1.0f + e);
      q[m] = (char)(int)rintf(basis * 254.0f - 127.0f);
      e *= R;
    }
    *(v8c*)(Ai8 + (size_t)idx * 8) = q;   // 8B coalesced store
  } else {
    const int o = blk - EXPAND_BLOCKS;
    const float4* row = coeffs4 + (size_t)o * (KDIM / 4);
    float4 v[8];
    float m = 0.0f;
#pragma unroll
    for (int j = 0; j < 8; ++j) {
      v[j] = row[tid + 256 * j];
      m = fmaxf(m, fmaxf(fmaxf(fabsf(v[j].x), fabsf(v[j].y)),
                         fmaxf(fabsf(v[j].z), fabsf(v[j].w))));
    }
#pragma unroll
    for (int off = 32; off; off >>= 1) m = fmaxf(m, __shfl_xor(m, off));
    __shared__ float wm[4];
    __shared__ int   wq[4];
    if ((tid & 63) == 0) wm[tid >> 6] = m;
    __syncthreads();
    const float M = fmaxf(fmaxf(fmaxf(wm[0], wm[1]), fmaxf(wm[2], wm[3])), 1e-30f);
    const float s = 127.0f / M;
    int qs = 0;
#pragma unroll
    for (int j = 0; j < 8; ++j) {
      int q0 = (int)rintf(v[j].x * s), q1 = (int)rintf(v[j].y * s);
      int q2 = (int)rintf(v[j].z * s), q3 = (int)rintf(v[j].w * s);
      Ci8i[(size_t)o * (KDIM / 4) + tid + 256 * j] =
          (q0 & 0xFF) | ((q1 & 0xFF) << 8) | ((q2 & 0xFF) << 16) | ((q3 & 0xFF) << 24);
      qs += q0 + q1 + q2 + q3;
    }
#pragma unroll
    for (int off = 32; off; off >>= 1) qs += __shfl_xor(qs, off);
    if ((tid & 63) == 0) wq[tid >> 6] = qs;
    __syncthreads();
    if (tid == 0) { maxrow[o] = M; qcsum[o] = wq[0] + wq[1] + wq[2] + wq[3]; }
  }
}

// ---------------- Phase 2: i8 16x16x64 MFMA GEMM, 256x128 / 2 blocks/CU ------------
// y_dot[m,n] = sum_k qa[m,k]*qc[n,k].
// Swizzle (T2, verified R2/R3/R5): LDS slot (row, gs) holds global 16B k-group
// gg = gs ^ ((row>>1)&3); staging LDS dest LINEAR in lane (global_load_lds rule);
// inverse swizzle on per-lane global source, forward swizzle on ds_read offset.
// Staging per wave per step: 3 gld16 (A rows wave*32..+32 in 2, B rows wave*16..+16
// in 1). Step t: vmcnt(3) = batch t landed (t+1's 3 loads still in flight) ->
// barrier -> 8 ds_read_b128 -> 16 MFMA (compiler inserts fine lgkm) -> barrier
// (slot drained) -> stage batch t+2 into slot t&1. Overlap across the 2 resident
// blocks (4 waves/SIMD) instead of within one lockstep block.
__global__ __launch_bounds__(512, 4) void gemm_kernel(
    const char* __restrict__ A, const char* __restrict__ C,
    unsigned short* __restrict__ partials) {
  __shared__ __align__(16) char As[2][BM * BKB];   // 2 x 16 KiB
  __shared__ __align__(16) char Bs[2][BN * BKB];   // 2 x  8 KiB

  // XCD-aware bijective remap: each XCD owns 64 consecutive logical blocks
  const int id = (blockIdx.x & 7) * (GRID_BLOCKS / 8) + (blockIdx.x >> 3);
  const int z  = id >> 7;          // 128 blocks per z-plane
  const int p  = id & 127;
  const int by = p >> 3;           // 16 M-tiles
  const int bx = p & 7;            // 8 N-tiles
  const int bm0 = by * BM;
  const int bn0 = bx * BN;
  const int kt0 = z * KZ;

  const int tid  = threadIdx.x;
  const int wave = tid >> 6;
  const int lane = tid & 63;
  const int quad = lane >> 4;
  const int lm   = lane & 15;
  const int wm   = (wave >> 1) * 64;   // 4 M-wave-groups
  const int wn   = (wave & 1) * 64;    // 2 N-wave-groups

  // staging decode: lane -> slot (row = rb+(lane>>2), gs = lane&3);
  // global group gg = gs ^ ((row>>1)&3)  [rb multiples of 16 -> key = (lane>>3)&3]
  const int r4 = lane >> 2;
  const int gg = (lane & 3) ^ ((lane >> 3) & 3);

  const char* pA0 = A + (size_t)(bm0 + wave * 32 + r4) * KDIM + kt0 + gg * 16;
  const char* pB0 = C + (size_t)(bn0 + wave * 16 + r4) * KDIM + kt0 + gg * 16;
  const int loA = wave * 32 * BKB;   // wave's A base within a slot (2 KiB)
  const int loB = wave * 16 * BKB;   // wave's B base within a slot (1 KiB)

  v4i acc[4][4] = {};
  const int kx = (quad ^ ((lm >> 1) & 3)) * 16;   // swizzled ds_read group offset

#define STAGE(SL)                                                            \
  {                                                                          \
    gld16(pA0,                      As[SL] + loA);                           \
    gld16(pA0 + (size_t)16 * KDIM,  As[SL] + loA + 16 * BKB);                \
    gld16(pB0,                      Bs[SL] + loB);                           \
    pA0 += BKB; pB0 += BKB;                                                  \
  }

  // prologue: stage batches 0,1 -> slots 0,1 (6 loads/wave in flight)
  STAGE(0);
  STAGE(1);

  for (int t = 0; t < KSTEPS; ++t) {
    const int cur = t & 1;
    if (t < KSTEPS - 1) {
      asm volatile("s_waitcnt vmcnt(3)" ::: "memory");   // batch t landed
    } else {
      asm volatile("s_waitcnt vmcnt(0)" ::: "memory");   // last batch
    }
    __builtin_amdgcn_sched_barrier(0);
    __builtin_amdgcn_s_barrier();

    const char* cA = As[cur];
    const char* cB = Bs[cur];
    v4i a[4], b[4];
#pragma unroll
    for (int f = 0; f < 4; ++f)
      a[f] = *(const v4i*)(cA + (wm + f * 16 + lm) * BKB + kx);
#pragma unroll
    for (int f = 0; f < 4; ++f)
      b[f] = *(const v4i*)(cB + (wn + f * 16 + lm) * BKB + kx);

    __builtin_amdgcn_s_setprio(1);
#pragma unroll
    for (int fm = 0; fm < 4; ++fm)
#pragma unroll
      for (int fn = 0; fn < 4; ++fn)
        acc[fm][fn] = __builtin_amdgcn_mfma_i32_16x16x64_i8(a[fm], b[fn], acc[fm][fn], 0, 0, 0);
    __builtin_amdgcn_s_setprio(0);

    __builtin_amdgcn_s_barrier();        // all waves done reading slot cur
    if (t < KSTEPS - 2) STAGE(cur);      // batch t+2 -> slot t&1 (WAR-safe)
  }
#undef STAGE

  // epilogue: C/D layout (dtype-independent): col = lane&15, row = quad*4 + reg
  unsigned short* out = partials + (size_t)z * BATCH * OUTC;
#pragma unroll
  for (int fm = 0; fm < 4; ++fm) {
    const int row0 = bm0 + wm + fm * 16 + quad * 4;
#pragma unroll
    for (int fn = 0; fn < 4; ++fn) {
      const int col = bn0 + wn + fn * 16 + lm;
#pragma unroll
      for (int r = 0; r < 4; ++r)
        out[(size_t)(row0 + r) * OUTC + col] = f2bf((float)acc[fm][fn][r]);
    }
  }
}

// ---------------- Phase 3: reduce + dequant ----------------
// y[b,o] = M[o]*(Sdot + 127*Qc[o]) / (127*254)
__global__ __launch_bounds__(256) void reduce_kernel(
    const unsigned short* __restrict__ P, const float* __restrict__ maxrow,
    const int* __restrict__ qcsum, float* __restrict__ out) {
  const size_t nel = (size_t)BATCH * OUTC;
  const size_t base = ((size_t)blockIdx.x * 256 + threadIdx.x) * 8;
  float s[8] = {};
#pragma unroll
  for (int t = 0; t < SPLITS; ++t) {
    v8s v = *(const v8s*)(P + t * nel + base);
#pragma unroll
    for (int j = 0; j < 8; ++j) s[j] += bf2f((unsigned short)v[j]);
  }
  const int o0 = (int)(base & (OUTC - 1));
  const float inv = 1.0f / 32258.0f;   // 127*254
#pragma unroll
  for (int j = 0; j < 8; ++j) {
    const float M = maxrow[o0 + j];
    const int   Q = qcsum[o0 + j];
    s[j] = M * (s[j] + 127.0f * (float)Q) * inv;
  }
  *(float4*)(out + base)     = float4{s[0], s[1], s[2], s[3]};
  *(float4*)(out + base + 4) = float4{s[4], s[5], s[6], s[7]};
}

extern "C" void kernel_launch(void* const* d_in, const int* in_sizes, int n_in,
                              void* d_out, int out_size, void* d_ws, size_t ws_size,
                              hipStream_t stream) {
  const float* x       = (const float*)d_in[0];
  const float* coeffs  = (const float*)d_in[1];
  const float* centers = (const float*)d_in[2];
  const float* slopes  = (const float*)d_in[3];
  const float* alpha   = (const float*)d_in[4];
  const float* beta    = (const float*)d_in[5];
  float* out = (float*)d_out;

  const size_t a_bytes    = (size_t)BATCH * KDIM;                 // 32 MiB i8
  const size_t c_bytes    = (size_t)OUTC * KDIM;                  // 8 MiB i8
  const size_t stat_bytes = OUTC * sizeof(float);                 // 4 KiB
  const size_t qcs_bytes  = OUTC * sizeof(int);                   // 4 KiB
  const size_t part_bytes = (size_t)SPLITS * BATCH * OUTC * 2;    // 32 MiB bf16
  if (ws_size < a_bytes + c_bytes + stat_bytes + qcs_bytes + part_bytes) return;

  char*  Ai8    = (char*)d_ws;
  char*  Ci8    = Ai8 + a_bytes;
  float* maxrow = (float*)(Ci8 + c_bytes);
  int*   qcsum  = (int*)((char*)maxrow + stat_bytes);
  unsigned short* parts = (unsigned short*)((char*)qcsum + qcs_bytes);

  prep_kernel<<<PREP_BLOCKS, 256, 0, stream>>>(
      x, (const float4*)coeffs, centers, slopes, alpha, beta,
      Ai8, (int*)Ci8, maxrow, qcsum);

  gemm_kernel<<<GRID_BLOCKS, 512, 0, stream>>>(Ai8, Ci8, parts);

  reduce_kernel<<<(int)((size_t)BATCH * OUTC / 8 / 256), 256, 0, stream>>>(
      parts, maxrow, qcsum, out);
}